// Round 2
// baseline (1327.344 us; speedup 1.0000x reference)
//
#include <hip/hip_runtime.h>
#include <cstdio>

typedef unsigned short u16;
typedef __attribute__((ext_vector_type(4))) float f32x4;
typedef __attribute__((ext_vector_type(8))) short s16x8;

#define DEV static __device__ __forceinline__

DEV float bf2f(u16 u) { union { unsigned int i; float f; } v; v.i = ((unsigned int)u) << 16; return v.f; }
DEV u16 f2bf(float f) {
  unsigned int x = __float_as_uint(f);
  unsigned int r = (x + 0x7fffu + ((x >> 16) & 1u)) >> 16;
  return (u16)r;
}

// ---------------------------------------------------------------------------
// Similarity GEMM: out[b][p][q] = (dot(A[b,:,p], B[b,:,q]) + 1) * 0.5  (fp32)
// A,B: [B][512][2304] fp32 (k-major, m/n contiguous). Tile 64x64, BK=32.
// ---------------------------------------------------------------------------
__global__ __launch_bounds__(256) void sim_gemm(const float* __restrict__ A,
    const float* __restrict__ Bm, float* __restrict__ out)
{
  __shared__ alignas(16) u16 Al[64][40];
  __shared__ alignas(16) u16 Bl[64][40];
  const int tid = threadIdx.x;
  const int bm = blockIdx.x, bn = blockIdx.y, b = blockIdx.z;
  const int lane = tid & 63, wv = tid >> 6, wr = wv >> 1, wc = wv & 1;
  const int smi = tid & 63, kq = tid >> 6;
  const float* Ab = A + (size_t)b * 512 * 2304 + bm * 64 + smi;
  const float* Bb = Bm + (size_t)b * 512 * 2304 + bn * 64 + smi;
  f32x4 acc00 = {0,0,0,0}, acc01 = {0,0,0,0}, acc10 = {0,0,0,0}, acc11 = {0,0,0,0};
  for (int k0 = 0; k0 < 512; k0 += 32) {
    s16x8 avv, bvv;
#pragma unroll
    for (int i = 0; i < 8; ++i) {
      const size_t ko = (size_t)(k0 + kq * 8 + i) * 2304;
      avv[i] = (short)f2bf(Ab[ko]);
      bvv[i] = (short)f2bf(Bb[ko]);
    }
    __syncthreads();
    *(s16x8*)&Al[smi][kq * 8] = avv;
    *(s16x8*)&Bl[smi][kq * 8] = bvv;
    __syncthreads();
    const int fr = lane & 15, kg = (lane >> 4) * 8;
    s16x8 a0 = *(const s16x8*)&Al[wr * 32 + fr][kg];
    s16x8 a1 = *(const s16x8*)&Al[wr * 32 + 16 + fr][kg];
    s16x8 b0 = *(const s16x8*)&Bl[wc * 32 + fr][kg];
    s16x8 b1 = *(const s16x8*)&Bl[wc * 32 + 16 + fr][kg];
    acc00 = __builtin_amdgcn_mfma_f32_16x16x32_bf16(a0, b0, acc00, 0, 0, 0);
    acc01 = __builtin_amdgcn_mfma_f32_16x16x32_bf16(a0, b1, acc01, 0, 0, 0);
    acc10 = __builtin_amdgcn_mfma_f32_16x16x32_bf16(a1, b0, acc10, 0, 0, 0);
    acc11 = __builtin_amdgcn_mfma_f32_16x16x32_bf16(a1, b1, acc11, 0, 0, 0);
  }
  float* ob = out + ((size_t)b * 2304 + bm * 64) * 2304 + bn * 64;
  const int col = lane & 15, rg = (lane >> 4) * 4;
#define SIM_ST(ACC, I, J) { \
    _Pragma("unroll") for (int r = 0; r < 4; ++r) { \
      int row = wr * 32 + (I) * 16 + rg + r; \
      int c = wc * 32 + (J) * 16 + col; \
      ob[(size_t)row * 2304 + c] = (ACC[r] + 1.0f) * 0.5f; } }
  SIM_ST(acc00, 0, 0) SIM_ST(acc01, 0, 1) SIM_ST(acc10, 1, 0) SIM_ST(acc11, 1, 1)
#undef SIM_ST
}

// ---------------------------------------------------------------------------
// Per-row stats of local_sim: cut = 4th-largest over q, mn = min over q.
// One block (256 thr) per row (B*2304 rows).
// ---------------------------------------------------------------------------
__global__ __launch_bounds__(256) void rowstats(const float* __restrict__ simL,
    float* __restrict__ cutv, float* __restrict__ mnv)
{
  const int row = blockIdx.x;
  const int tid = threadIdx.x;
  const float* r = simL + (size_t)row * 2304;
  float t0 = -1e30f, t1 = -1e30f, t2 = -1e30f, t3 = -1e30f, mn = 1e30f;
  for (int i = tid; i < 2304; i += 256) {
    float v = r[i];
    mn = fminf(mn, v);
    if (v > t3) {
      if (v > t2) { t3 = t2; if (v > t1) { t2 = t1; if (v > t0) { t1 = t0; t0 = v; } else t1 = v; } else t2 = v; }
      else t3 = v;
    }
  }
  __shared__ float s4[256][4];
  __shared__ float smv[256];
  s4[tid][0] = t0; s4[tid][1] = t1; s4[tid][2] = t2; s4[tid][3] = t3;
  smv[tid] = mn;
  __syncthreads();
  for (int s = 128; s > 0; s >>= 1) {
    if (tid < s) {
      float a0 = s4[tid][0], a1 = s4[tid][1], a2 = s4[tid][2], a3 = s4[tid][3];
      float b0 = s4[tid + s][0], b1 = s4[tid + s][1], b2 = s4[tid + s][2], b3 = s4[tid + s][3];
      float m0 = fmaxf(a0, b3), m1 = fmaxf(a1, b2), m2 = fmaxf(a2, b1), m3 = fmaxf(a3, b0);
      float c0 = fmaxf(m0, m2), c2 = fminf(m0, m2), c1 = fmaxf(m1, m3), c3 = fminf(m1, m3);
      s4[tid][0] = fmaxf(c0, c1); s4[tid][1] = fminf(c0, c1);
      s4[tid][2] = fmaxf(c2, c3); s4[tid][3] = fminf(c2, c3);
      smv[tid] = fminf(smv[tid], smv[tid + s]);
    }
    __syncthreads();
  }
  if (tid == 0) { cutv[row] = s4[0][3]; mnv[row] = smv[0]; }
}

__global__ __launch_bounds__(256) void zero_f(float* __restrict__ p, int n)
{
  int i = blockIdx.x * 256 + threadIdx.x;
  if (i < n) p[i] = 0.0f;
}

// global score: msc[b][chBase+c][q] = max_p sim[b][p][q] * seg[b][c][p]
__global__ __launch_bounds__(256) void score_global(const float* __restrict__ sim,
    const float* __restrict__ seg, float* __restrict__ msc, int chBase)
{
  const int b = blockIdx.z;
  const int q = blockIdx.x * 256 + threadIdx.x;
  const int p0 = blockIdx.y * 128;
  const float* sp = sim + ((size_t)b * 2304 + p0) * 2304 + q;
  const float* sg = seg + (size_t)b * 2 * 2304;
  float m0 = 0.0f, m1 = 0.0f;
  for (int p = 0; p < 128; ++p) {
    float sv = sp[(size_t)p * 2304];
    float s0 = sg[p0 + p];
    float s1 = sg[2304 + p0 + p];
    m0 = fmaxf(m0, sv * s0);
    m1 = fmaxf(m1, sv * s1);
  }
  atomicMax((int*)&msc[((size_t)b * 4 + chBase) * 2304 + q], __float_as_int(m0));
  atomicMax((int*)&msc[((size_t)b * 4 + chBase + 1) * 2304 + q], __float_as_int(m1));
}

// local score with per-row top4 threshold masking
__global__ __launch_bounds__(256) void score_local(const float* __restrict__ sim,
    const float* __restrict__ seg, const float* __restrict__ cutv,
    const float* __restrict__ mnv, float* __restrict__ msc, int chBase)
{
  const int b = blockIdx.z;
  const int q = blockIdx.x * 256 + threadIdx.x;
  const int p0 = blockIdx.y * 128;
  const float* sp = sim + ((size_t)b * 2304 + p0) * 2304 + q;
  const float* sg = seg + (size_t)b * 2 * 2304;
  const float* cu = cutv + (size_t)b * 2304 + p0;
  const float* ml = mnv + (size_t)b * 2304 + p0;
  float m0 = 0.0f, m1 = 0.0f;
  for (int p = 0; p < 128; ++p) {
    float sv = sp[(size_t)p * 2304];
    float cut = cu[p], mnr = ml[p];
    float mv = (sv < cut) ? mnr : sv;
    float s0 = sg[p0 + p];
    float s1 = sg[2304 + p0 + p];
    m0 = fmaxf(m0, mv * s0);
    m1 = fmaxf(m1, mv * s1);
  }
  atomicMax((int*)&msc[((size_t)b * 4 + chBase) * 2304 + q], __float_as_int(m0));
  atomicMax((int*)&msc[((size_t)b * 4 + chBase + 1) * 2304 + q], __float_as_int(m1));
}

// scores fp32 -> bf16 into x1 channels 256..259
__global__ __launch_bounds__(256) void fill_scores(const float* __restrict__ msc,
    u16* __restrict__ x1)
{
  int idx = blockIdx.x * 256 + threadIdx.x;
  if (idx >= 2 * 4 * 2304) return;
  int b = idx / (4 * 2304);
  int r = idx % (4 * 2304);
  int c = r / 2304, q = r % 2304;
  x1[((size_t)b * 516 + 256 + c) * 2304 + q] = f2bf(msc[idx]);
}

// mask_feats fp32 -> x1 channels 260..515 bf16
__global__ __launch_bounds__(256) void copy_mask(const float* __restrict__ mask,
    u16* __restrict__ x1)
{
  int idx = blockIdx.x * 256 + threadIdx.x;
  if (idx >= 2 * 256 * 2304) return;
  int b = idx / (256 * 2304);
  int r = idx % (256 * 2304);
  x1[(size_t)b * 516 * 2304 + 260 * 2304 + r] = f2bf(mask[idx]);
}

// repack blend weights: w[oc][ic][3][3] fp32 -> wr[tap][oc][ICp] bf16 (zero-pad ic)
__global__ __launch_bounds__(256) void repack(const float* __restrict__ w,
    u16* __restrict__ wr, int IC, int ICp)
{
  int idx = blockIdx.x * 256 + threadIdx.x;
  int total = 9 * 256 * ICp;
  if (idx >= total) return;
  int ic = idx % ICp;
  int oc = (idx / ICp) % 256;
  int tap = idx / (ICp * 256);
  wr[idx] = (ic < IC) ? f2bf(w[((size_t)oc * IC + ic) * 9 + tap]) : (u16)0;
}

// ---------------------------------------------------------------------------
// 1x1 conv (GEMM): Y[b][oc][n] = relu(bias[oc] + sum_k W[oc][k] * X[b][k][n])
// X, W fp32 (d_in); Y bf16 with OCtot channel stride. Tile 64x64, BK=32.
// ---------------------------------------------------------------------------
__global__ __launch_bounds__(256) void conv1x1(const float* __restrict__ X,
    const float* __restrict__ Wt, const float* __restrict__ bias,
    u16* __restrict__ Y, int K, int N, int OCtot)
{
  __shared__ alignas(16) u16 Al[64][40];
  __shared__ alignas(16) u16 Bl[64][40];
  const int tid = threadIdx.x;
  const int n0 = blockIdx.x * 64, m0 = blockIdx.y * 64, b = blockIdx.z;
  const int lane = tid & 63, wv = tid >> 6, wr = wv >> 1, wc = wv & 1;
  const int am = tid >> 2, akq = tid & 3;
  const int sn = tid & 63, kq = tid >> 6;
  const float* Xb = X + (size_t)b * K * N + n0 + sn;
  f32x4 acc00 = {0,0,0,0}, acc01 = {0,0,0,0}, acc10 = {0,0,0,0}, acc11 = {0,0,0,0};
  for (int k0 = 0; k0 < K; k0 += 32) {
    s16x8 avv, bvv;
#pragma unroll
    for (int i = 0; i < 8; ++i)
      avv[i] = (short)f2bf(Wt[(size_t)(m0 + am) * K + k0 + akq * 8 + i]);
#pragma unroll
    for (int i = 0; i < 8; ++i)
      bvv[i] = (short)f2bf(Xb[(size_t)(k0 + kq * 8 + i) * N]);
    __syncthreads();
    *(s16x8*)&Al[am][akq * 8] = avv;
    *(s16x8*)&Bl[sn][kq * 8] = bvv;
    __syncthreads();
    const int fr = lane & 15, kg = (lane >> 4) * 8;
    s16x8 a0 = *(const s16x8*)&Al[wr * 32 + fr][kg];
    s16x8 a1 = *(const s16x8*)&Al[wr * 32 + 16 + fr][kg];
    s16x8 b0 = *(const s16x8*)&Bl[wc * 32 + fr][kg];
    s16x8 b1 = *(const s16x8*)&Bl[wc * 32 + 16 + fr][kg];
    acc00 = __builtin_amdgcn_mfma_f32_16x16x32_bf16(a0, b0, acc00, 0, 0, 0);
    acc01 = __builtin_amdgcn_mfma_f32_16x16x32_bf16(a0, b1, acc01, 0, 0, 0);
    acc10 = __builtin_amdgcn_mfma_f32_16x16x32_bf16(a1, b0, acc10, 0, 0, 0);
    acc11 = __builtin_amdgcn_mfma_f32_16x16x32_bf16(a1, b1, acc11, 0, 0, 0);
  }
  const int col = lane & 15, rg = (lane >> 4) * 4;
#define CV_ST(ACC, I, J) { \
    _Pragma("unroll") for (int r = 0; r < 4; ++r) { \
      int oc = m0 + wr * 32 + (I) * 16 + rg + r; \
      int nn = n0 + wc * 32 + (J) * 16 + col; \
      float v = ACC[r] + bias[oc]; \
      v = fmaxf(v, 0.0f); \
      Y[((size_t)b * OCtot + oc) * N + nn] = f2bf(v); } }
  CV_ST(acc00, 0, 0) CV_ST(acc01, 0, 1) CV_ST(acc10, 1, 0) CV_ST(acc11, 1, 1)
#undef CV_ST
}

// ---------------------------------------------------------------------------
// 3x3 conv pad1 + relu, implicit GEMM. X: [B][IC][WD*WD] bf16,
// Wr: [9][256][ICp] bf16, bias fp32, Y: [B][256][WD*WD] bf16.
// ---------------------------------------------------------------------------
template<int WD>
__global__ __launch_bounds__(256) void blend3x3(const u16* __restrict__ X,
    const u16* __restrict__ Wr, const float* __restrict__ bias,
    u16* __restrict__ Y, int IC, int ICp)
{
  constexpr int HW = WD * WD;
  __shared__ alignas(16) u16 Al[64][40];
  __shared__ alignas(16) u16 Bl[64][40];
  const int tid = threadIdx.x;
  const int n0 = blockIdx.x * 64, m0 = blockIdx.y * 64, b = blockIdx.z;
  const int lane = tid & 63, wv = tid >> 6, wr = wv >> 1, wc = wv & 1;
  const int am = tid >> 2, akq = tid & 3;
  const int sn = tid & 63, kq = tid >> 6;
  const int pix = n0 + sn;
  const int py = pix / WD, px = pix % WD;
  const u16* Xb = X + (size_t)b * IC * HW;
  f32x4 acc00 = {0,0,0,0}, acc01 = {0,0,0,0}, acc10 = {0,0,0,0}, acc11 = {0,0,0,0};
  for (int tap = 0; tap < 9; ++tap) {
    const int dy = tap / 3 - 1, dx = tap % 3 - 1;
    const int sy = py + dy, sx = px + dx;
    const bool vsp = ((unsigned)sy < (unsigned)WD) && ((unsigned)sx < (unsigned)WD);
    const u16* Xt = Xb + sy * WD + sx;
    const u16* Wt = Wr + (size_t)tap * 256 * ICp;
    for (int k0 = 0; k0 < ICp; k0 += 32) {
      s16x8 avv = *(const s16x8*)&Wt[(size_t)(m0 + am) * ICp + k0 + akq * 8];
      s16x8 bvv;
#pragma unroll
      for (int i = 0; i < 8; ++i) {
        int k = k0 + kq * 8 + i;
        bool ok = vsp && (k < IC);
        bvv[i] = ok ? (short)Xt[(size_t)k * HW] : (short)0;
      }
      __syncthreads();
      *(s16x8*)&Al[am][akq * 8] = avv;
      *(s16x8*)&Bl[sn][kq * 8] = bvv;
      __syncthreads();
      const int fr = lane & 15, kg = (lane >> 4) * 8;
      s16x8 a0 = *(const s16x8*)&Al[wr * 32 + fr][kg];
      s16x8 a1 = *(const s16x8*)&Al[wr * 32 + 16 + fr][kg];
      s16x8 b0 = *(const s16x8*)&Bl[wc * 32 + fr][kg];
      s16x8 b1 = *(const s16x8*)&Bl[wc * 32 + 16 + fr][kg];
      acc00 = __builtin_amdgcn_mfma_f32_16x16x32_bf16(a0, b0, acc00, 0, 0, 0);
      acc01 = __builtin_amdgcn_mfma_f32_16x16x32_bf16(a0, b1, acc01, 0, 0, 0);
      acc10 = __builtin_amdgcn_mfma_f32_16x16x32_bf16(a1, b0, acc10, 0, 0, 0);
      acc11 = __builtin_amdgcn_mfma_f32_16x16x32_bf16(a1, b1, acc11, 0, 0, 0);
    }
  }
  const int col = lane & 15, rg = (lane >> 4) * 4;
#define BL_ST(ACC, I, J) { \
    _Pragma("unroll") for (int r = 0; r < 4; ++r) { \
      int oc = m0 + wr * 32 + (I) * 16 + rg + r; \
      int nn = n0 + wc * 32 + (J) * 16 + col; \
      float v = ACC[r] + bias[oc]; \
      v = fmaxf(v, 0.0f); \
      Y[((size_t)b * 256 + oc) * HW + nn] = f2bf(v); } }
  BL_ST(acc00, 0, 0) BL_ST(acc01, 0, 1) BL_ST(acc10, 1, 0) BL_ST(acc11, 1, 1)
#undef BL_ST
}

// ---------------------------------------------------------------------------
// ConvTranspose2d(256->2, k=4, s=2, p=1). X: [B][256][WIN][WIN] bf16,
// Wd: [256][2][4][4] fp32, write into Y (bf16) channels coff..coff+1 of OCtot.
// ---------------------------------------------------------------------------
template<int WIN>
__global__ __launch_bounds__(256) void deconv_s2(const u16* __restrict__ X,
    const float* __restrict__ Wd, const float* __restrict__ bias,
    u16* __restrict__ Y, int OCtot, int coff)
{
  __shared__ u16 wl[4][4][2][256];
  for (int i = threadIdx.x; i < 8192; i += 256) {
    int kx = i & 3, ky = (i >> 2) & 3, oc = (i >> 4) & 1, ic = i >> 5;
    wl[ky][kx][oc][ic] = f2bf(Wd[i]);
  }
  __syncthreads();
  constexpr int HWin = WIN * WIN;
  constexpr int WO = WIN * 2;
  const int b = blockIdx.y;
  const int opix = blockIdx.x * 256 + threadIdx.x;
  const int oy = opix / WO, ox = opix % WO;
  float acc0 = bias[0], acc1 = bias[1];
  const u16* Xb = X + (size_t)b * 256 * HWin;
  const int ry = (oy + 1) & 1, rx = (ox + 1) & 1;
#pragma unroll
  for (int ty = 0; ty < 2; ++ty) {
    const int ky = ry + 2 * ty, yy = oy + 1 - ky;
    const int iy = yy >> 1;
    if (yy < 0 || iy >= WIN) continue;
#pragma unroll
    for (int tx = 0; tx < 2; ++tx) {
      const int kx = rx + 2 * tx, xx = ox + 1 - kx;
      const int ix = xx >> 1;
      if (xx < 0 || ix >= WIN) continue;
      const u16* xp = Xb + iy * WIN + ix;
#pragma unroll 4
      for (int ic = 0; ic < 256; ++ic) {
        float xv = bf2f(xp[(size_t)ic * HWin]);
        acc0 += xv * bf2f(wl[ky][kx][0][ic]);
        acc1 += xv * bf2f(wl[ky][kx][1][ic]);
      }
    }
  }
  Y[((size_t)b * OCtot + coff) * (WO * WO) + opix] = f2bf(acc0);
  Y[((size_t)b * OCtot + coff + 1) * (WO * WO) + opix] = f2bf(acc1);
}

// ConvTranspose2d(256->2, k=6, s=4, p=1): 192x192 -> 768x768, to d_out (fp32).
__global__ __launch_bounds__(256) void deconv_s4(const u16* __restrict__ X,
    const float* __restrict__ Wd, const float* __restrict__ bias,
    float* __restrict__ Y)
{
  __shared__ u16 wl[6][6][2][256]; // 36 KB
  for (int i = threadIdx.x; i < 256 * 2 * 36; i += 256) {
    int kx = i % 6, ky = (i / 6) % 6, oc = (i / 36) % 2, ic = i / 72;
    wl[ky][kx][oc][ic] = f2bf(Wd[i]);
  }
  __syncthreads();
  const int b = blockIdx.y;
  const int opix = blockIdx.x * 256 + threadIdx.x;
  const int oy = opix / 768, ox = opix % 768;
  float acc0 = bias[0], acc1 = bias[1];
  const u16* Xb = X + (size_t)b * 256 * 192 * 192;
  const int ry = (oy + 1) & 3, rx = (ox + 1) & 3;
#pragma unroll
  for (int ty = 0; ty < 2; ++ty) {
    int ky = ry + 4 * ty;
    if (ky > 5) break;
    int yy = oy + 1 - ky;
    if (yy < 0) continue;
    int iy = yy >> 2;
    if (iy >= 192) continue;
#pragma unroll
    for (int tx = 0; tx < 2; ++tx) {
      int kx = rx + 4 * tx;
      if (kx > 5) break;
      int xx = ox + 1 - kx;
      if (xx < 0) continue;
      int ix = xx >> 2;
      if (ix >= 192) continue;
      const u16* xp = Xb + iy * 192 + ix;
#pragma unroll 4
      for (int ic = 0; ic < 256; ++ic) {
        float xv = bf2f(xp[(size_t)ic * 192 * 192]);
        acc0 += xv * bf2f(wl[ky][kx][0][ic]);
        acc1 += xv * bf2f(wl[ky][kx][1][ic]);
      }
    }
  }
  Y[(size_t)b * 2 * 589824 + opix] = acc0;
  Y[((size_t)b * 2 + 1) * 589824 + opix] = acc1;
}

// ---------------------------------------------------------------------------
extern "C" void kernel_launch(void* const* d_in, const int* in_sizes, int n_in,
                              void* d_out, int out_size, void* d_ws, size_t ws_size,
                              hipStream_t stream)
{
  const float* feats_s16 = (const float*)d_in[0];
  const float* feats_s8  = (const float*)d_in[1];
  const float* feats_s4  = (const float*)d_in[2];
  const float* key       = (const float*)d_in[3];
  const float* init_key  = (const float*)d_in[4];
  const float* prev_key  = (const float*)d_in[5];
  const float* init_seg  = (const float*)d_in[6];
  const float* prev_seg  = (const float*)d_in[7];
  const float* mask_f    = (const float*)d_in[8];
  const float* w_conv1 = (const float*)d_in[9];  const float* b_conv1 = (const float*)d_in[10];
  const float* w_blend1= (const float*)d_in[11]; const float* b_blend1= (const float*)d_in[12];
  const float* w_dec1  = (const float*)d_in[13]; const float* b_dec1  = (const float*)d_in[14];
  const float* w_conv2 = (const float*)d_in[15]; const float* b_conv2 = (const float*)d_in[16];
  const float* w_blend2= (const float*)d_in[17]; const float* b_blend2= (const float*)d_in[18];
  const float* w_dec2  = (const float*)d_in[19]; const float* b_dec2  = (const float*)d_in[20];
  const float* w_conv3 = (const float*)d_in[21]; const float* b_conv3 = (const float*)d_in[22];
  const float* w_blend3= (const float*)d_in[23]; const float* b_blend3= (const float*)d_in[24];
  const float* w_dec3  = (const float*)d_in[25]; const float* b_dec3  = (const float*)d_in[26];

  char* ws = (char*)d_ws;
  size_t o = 0;
  auto take = [&](size_t n) { size_t r = o; o += (n + 255) & ~(size_t)255; return r; };
  float* simG = (float*)(ws + take((size_t)2 * 2304 * 2304 * 4));
  float* simL = (float*)(ws + take((size_t)2 * 2304 * 2304 * 4));
  float* cutv = (float*)(ws + take((size_t)2 * 2304 * 4));
  float* mnv  = (float*)(ws + take((size_t)2 * 2304 * 4));
  float* msc  = (float*)(ws + take((size_t)2 * 4 * 2304 * 4));
  u16* x1  = (u16*)(ws + take((size_t)2 * 516 * 2304 * 2));
  u16* b1o = (u16*)(ws + take((size_t)2 * 256 * 2304 * 2));
  u16* x2  = (u16*)(ws + take((size_t)2 * 258 * 9216 * 2));
  u16* b2o = (u16*)(ws + take((size_t)2 * 256 * 9216 * 2));
  u16* x3  = (u16*)(ws + take((size_t)2 * 258 * 36864 * 2));
  u16* b3o = (u16*)(ws + take((size_t)2 * 256 * 36864 * 2));
  u16* wr1 = (u16*)(ws + take((size_t)9 * 256 * 544 * 2));
  u16* wr2 = (u16*)(ws + take((size_t)9 * 256 * 288 * 2));
  u16* wr3 = (u16*)(ws + take((size_t)9 * 256 * 288 * 2));
  if (o > ws_size) {
    fprintf(stderr, "kernel_launch: ws too small: need %zu, have %zu\n", o, ws_size);
    return;
  }

  // weight repacks (fp32 -> bf16)
  repack<<<dim3((9 * 256 * 544 + 255) / 256), 256, 0, stream>>>(w_blend1, wr1, 516, 544);
  repack<<<dim3((9 * 256 * 288 + 255) / 256), 256, 0, stream>>>(w_blend2, wr2, 258, 288);
  repack<<<dim3((9 * 256 * 288 + 255) / 256), 256, 0, stream>>>(w_blend3, wr3, 258, 288);

  // similarity matrices
  sim_gemm<<<dim3(36, 36, 2), 256, 0, stream>>>(init_key, key, simG);
  sim_gemm<<<dim3(36, 36, 2), 256, 0, stream>>>(prev_key, key, simL);

  // matching scores
  rowstats<<<dim3(2 * 2304), 256, 0, stream>>>(simL, cutv, mnv);
  zero_f<<<dim3(72), 256, 0, stream>>>(msc, 2 * 4 * 2304);
  score_global<<<dim3(9, 18, 2), 256, 0, stream>>>(simG, init_seg, msc, 0);
  score_local<<<dim3(9, 18, 2), 256, 0, stream>>>(simL, prev_seg, cutv, mnv, msc, 2);

  // stage 1
  conv1x1<<<dim3(36, 4, 2), 256, 0, stream>>>(feats_s16, w_conv1, b_conv1, x1, 1024, 2304, 516);
  fill_scores<<<dim3(72), 256, 0, stream>>>(msc, x1);
  copy_mask<<<dim3(4608), 256, 0, stream>>>(mask_f, x1);
  blend3x3<48><<<dim3(36, 4, 2), 256, 0, stream>>>(x1, wr1, b_blend1, b1o, 516, 544);
  deconv_s2<48><<<dim3(36, 2), 256, 0, stream>>>(b1o, w_dec1, b_dec1, x2, 258, 256);

  // stage 2
  conv1x1<<<dim3(144, 4, 2), 256, 0, stream>>>(feats_s8, w_conv2, b_conv2, x2, 512, 9216, 258);
  blend3x3<96><<<dim3(144, 4, 2), 256, 0, stream>>>(x2, wr2, b_blend2, b2o, 258, 288);
  deconv_s2<96><<<dim3(144, 2), 256, 0, stream>>>(b2o, w_dec2, b_dec2, x3, 258, 256);

  // stage 3
  conv1x1<<<dim3(576, 4, 2), 256, 0, stream>>>(feats_s4, w_conv3, b_conv3, x3, 256, 36864, 258);
  blend3x3<192><<<dim3(576, 4, 2), 256, 0, stream>>>(x3, wr3, b_blend3, b3o, 258, 288);
  deconv_s4<<<dim3(2304, 2), 256, 0, stream>>>(b3o, w_dec3, b_dec3, (float*)d_out);
}

// Round 3
// 796.379 us; speedup vs baseline: 1.6667x; 1.6667x over previous
//
#include <hip/hip_runtime.h>
#include <cstdio>

typedef unsigned short u16;
typedef __attribute__((ext_vector_type(4))) float f32x4;
typedef __attribute__((ext_vector_type(8))) short s16x8;

#define DEV static __device__ __forceinline__

DEV float bf2f(u16 u) { union { unsigned int i; float f; } v; v.i = ((unsigned int)u) << 16; return v.f; }
DEV u16 f2bf(float f) {
  unsigned int x = __float_as_uint(f);
  unsigned int r = (x + 0x7fffu + ((x >> 16) & 1u)) >> 16;
  return (u16)r;
}

// ---------------------------------------------------------------------------
// Similarity GEMM: out[b][p][q] = (dot(A[b,:,p], B[b,:,q]) + 1) * 0.5  (fp32)
// A,B: [B][512][2304] fp32 (k-major, m/n contiguous). Tile 64x64, BK=32.
// ---------------------------------------------------------------------------
__global__ __launch_bounds__(256) void sim_gemm(const float* __restrict__ A,
    const float* __restrict__ Bm, float* __restrict__ out)
{
  __shared__ alignas(16) u16 Al[64][40];
  __shared__ alignas(16) u16 Bl[64][40];
  const int tid = threadIdx.x;
  const int bm = blockIdx.x, bn = blockIdx.y, b = blockIdx.z;
  const int lane = tid & 63, wv = tid >> 6, wr = wv >> 1, wc = wv & 1;
  const int smi = tid & 63, kq = tid >> 6;
  const float* Ab = A + (size_t)b * 512 * 2304 + bm * 64 + smi;
  const float* Bb = Bm + (size_t)b * 512 * 2304 + bn * 64 + smi;
  f32x4 acc00 = {0,0,0,0}, acc01 = {0,0,0,0}, acc10 = {0,0,0,0}, acc11 = {0,0,0,0};
  for (int k0 = 0; k0 < 512; k0 += 32) {
    s16x8 avv, bvv;
#pragma unroll
    for (int i = 0; i < 8; ++i) {
      const size_t ko = (size_t)(k0 + kq * 8 + i) * 2304;
      avv[i] = (short)f2bf(Ab[ko]);
      bvv[i] = (short)f2bf(Bb[ko]);
    }
    __syncthreads();
    *(s16x8*)&Al[smi][kq * 8] = avv;
    *(s16x8*)&Bl[smi][kq * 8] = bvv;
    __syncthreads();
    const int fr = lane & 15, kg = (lane >> 4) * 8;
    s16x8 a0 = *(const s16x8*)&Al[wr * 32 + fr][kg];
    s16x8 a1 = *(const s16x8*)&Al[wr * 32 + 16 + fr][kg];
    s16x8 b0 = *(const s16x8*)&Bl[wc * 32 + fr][kg];
    s16x8 b1 = *(const s16x8*)&Bl[wc * 32 + 16 + fr][kg];
    acc00 = __builtin_amdgcn_mfma_f32_16x16x32_bf16(a0, b0, acc00, 0, 0, 0);
    acc01 = __builtin_amdgcn_mfma_f32_16x16x32_bf16(a0, b1, acc01, 0, 0, 0);
    acc10 = __builtin_amdgcn_mfma_f32_16x16x32_bf16(a1, b0, acc10, 0, 0, 0);
    acc11 = __builtin_amdgcn_mfma_f32_16x16x32_bf16(a1, b1, acc11, 0, 0, 0);
  }
  float* ob = out + ((size_t)b * 2304 + bm * 64) * 2304 + bn * 64;
  const int col = lane & 15, rg = (lane >> 4) * 4;
#define SIM_ST(ACC, I, J) { \
    _Pragma("unroll") for (int r = 0; r < 4; ++r) { \
      int row = wr * 32 + (I) * 16 + rg + r; \
      int c = wc * 32 + (J) * 16 + col; \
      ob[(size_t)row * 2304 + c] = (ACC[r] + 1.0f) * 0.5f; } }
  SIM_ST(acc00, 0, 0) SIM_ST(acc01, 0, 1) SIM_ST(acc10, 1, 0) SIM_ST(acc11, 1, 1)
#undef SIM_ST
}

// ---------------------------------------------------------------------------
// Per-row stats of local_sim: cut = 4th-largest over q, mn = min over q.
// ---------------------------------------------------------------------------
__global__ __launch_bounds__(256) void rowstats(const float* __restrict__ simL,
    float* __restrict__ cutv, float* __restrict__ mnv)
{
  const int row = blockIdx.x;
  const int tid = threadIdx.x;
  const float* r = simL + (size_t)row * 2304;
  float t0 = -1e30f, t1 = -1e30f, t2 = -1e30f, t3 = -1e30f, mn = 1e30f;
  for (int i = tid; i < 2304; i += 256) {
    float v = r[i];
    mn = fminf(mn, v);
    if (v > t3) {
      if (v > t2) { t3 = t2; if (v > t1) { t2 = t1; if (v > t0) { t1 = t0; t0 = v; } else t1 = v; } else t2 = v; }
      else t3 = v;
    }
  }
  __shared__ float s4[256][4];
  __shared__ float smv[256];
  s4[tid][0] = t0; s4[tid][1] = t1; s4[tid][2] = t2; s4[tid][3] = t3;
  smv[tid] = mn;
  __syncthreads();
  for (int s = 128; s > 0; s >>= 1) {
    if (tid < s) {
      float a0 = s4[tid][0], a1 = s4[tid][1], a2 = s4[tid][2], a3 = s4[tid][3];
      float b0 = s4[tid + s][0], b1 = s4[tid + s][1], b2 = s4[tid + s][2], b3 = s4[tid + s][3];
      float m0 = fmaxf(a0, b3), m1 = fmaxf(a1, b2), m2 = fmaxf(a2, b1), m3 = fmaxf(a3, b0);
      float c0 = fmaxf(m0, m2), c2 = fminf(m0, m2), c1 = fmaxf(m1, m3), c3 = fminf(m1, m3);
      s4[tid][0] = fmaxf(c0, c1); s4[tid][1] = fminf(c0, c1);
      s4[tid][2] = fmaxf(c2, c3); s4[tid][3] = fminf(c2, c3);
      smv[tid] = fminf(smv[tid], smv[tid + s]);
    }
    __syncthreads();
  }
  if (tid == 0) { cutv[row] = s4[0][3]; mnv[row] = smv[0]; }
}

__global__ __launch_bounds__(256) void zero_f(float* __restrict__ p, int n)
{
  int i = blockIdx.x * 256 + threadIdx.x;
  if (i < n) p[i] = 0.0f;
}

// global score: msc[b][chBase+c][q] = max_p sim[b][p][q] * seg[b][c][p]
__global__ __launch_bounds__(256) void score_global(const float* __restrict__ sim,
    const float* __restrict__ seg, float* __restrict__ msc, int chBase)
{
  const int b = blockIdx.z;
  const int q = blockIdx.x * 256 + threadIdx.x;
  const int p0 = blockIdx.y * 128;
  const float* sp = sim + ((size_t)b * 2304 + p0) * 2304 + q;
  const float* sg = seg + (size_t)b * 2 * 2304;
  float m0 = 0.0f, m1 = 0.0f;
  for (int p = 0; p < 128; ++p) {
    float sv = sp[(size_t)p * 2304];
    float s0 = sg[p0 + p];
    float s1 = sg[2304 + p0 + p];
    m0 = fmaxf(m0, sv * s0);
    m1 = fmaxf(m1, sv * s1);
  }
  atomicMax((int*)&msc[((size_t)b * 4 + chBase) * 2304 + q], __float_as_int(m0));
  atomicMax((int*)&msc[((size_t)b * 4 + chBase + 1) * 2304 + q], __float_as_int(m1));
}

// local score with per-row top4 threshold masking
__global__ __launch_bounds__(256) void score_local(const float* __restrict__ sim,
    const float* __restrict__ seg, const float* __restrict__ cutv,
    const float* __restrict__ mnv, float* __restrict__ msc, int chBase)
{
  const int b = blockIdx.z;
  const int q = blockIdx.x * 256 + threadIdx.x;
  const int p0 = blockIdx.y * 128;
  const float* sp = sim + ((size_t)b * 2304 + p0) * 2304 + q;
  const float* sg = seg + (size_t)b * 2 * 2304;
  const float* cu = cutv + (size_t)b * 2304 + p0;
  const float* ml = mnv + (size_t)b * 2304 + p0;
  float m0 = 0.0f, m1 = 0.0f;
  for (int p = 0; p < 128; ++p) {
    float sv = sp[(size_t)p * 2304];
    float cut = cu[p], mnr = ml[p];
    float mv = (sv < cut) ? mnr : sv;
    float s0 = sg[p0 + p];
    float s1 = sg[2304 + p0 + p];
    m0 = fmaxf(m0, mv * s0);
    m1 = fmaxf(m1, mv * s1);
  }
  atomicMax((int*)&msc[((size_t)b * 4 + chBase) * 2304 + q], __float_as_int(m0));
  atomicMax((int*)&msc[((size_t)b * 4 + chBase + 1) * 2304 + q], __float_as_int(m1));
}

// scores fp32 -> bf16 into x1 channels 256..259
__global__ __launch_bounds__(256) void fill_scores(const float* __restrict__ msc,
    u16* __restrict__ x1)
{
  int idx = blockIdx.x * 256 + threadIdx.x;
  if (idx >= 2 * 4 * 2304) return;
  int b = idx / (4 * 2304);
  int r = idx % (4 * 2304);
  int c = r / 2304, q = r % 2304;
  x1[((size_t)b * 516 + 256 + c) * 2304 + q] = f2bf(msc[idx]);
}

// mask_feats fp32 -> x1 channels 260..515 bf16
__global__ __launch_bounds__(256) void copy_mask(const float* __restrict__ mask,
    u16* __restrict__ x1)
{
  int idx = blockIdx.x * 256 + threadIdx.x;
  if (idx >= 2 * 256 * 2304) return;
  int b = idx / (256 * 2304);
  int r = idx % (256 * 2304);
  x1[(size_t)b * 516 * 2304 + 260 * 2304 + r] = f2bf(mask[idx]);
}

// repack blend weights: w[oc][ic][3][3] fp32 -> wr[tap][oc][ICp] bf16 (zero-pad ic)
__global__ __launch_bounds__(256) void repack(const float* __restrict__ w,
    u16* __restrict__ wr, int IC, int ICp)
{
  int idx = blockIdx.x * 256 + threadIdx.x;
  int total = 9 * 256 * ICp;
  if (idx >= total) return;
  int ic = idx % ICp;
  int oc = (idx / ICp) % 256;
  int tap = idx / (ICp * 256);
  wr[idx] = (ic < IC) ? f2bf(w[((size_t)oc * IC + ic) * 9 + tap]) : (u16)0;
}

// repack deconv weights: w[ic][oc][KSZ][KSZ] fp32 -> wr[MT*16][1024] bf16.
// m = ph*2+oc, ph = ry*S+rx (pad rows >= 2*S*S zero);
// k = (dy*2+dx)*256 + ic; val = W[ic][oc][ry+S*dy][rx+S*dx] or 0 if tap OOB.
__global__ __launch_bounds__(256) void repack_dec(const float* __restrict__ w,
    u16* __restrict__ wr, int S, int KSZ, int MT)
{
  int idx = blockIdx.x * 256 + threadIdx.x;
  int total = MT * 16 * 1024;
  if (idx >= total) return;
  int m = idx >> 10, k = idx & 1023;
  int oc = m & 1, ph = m >> 1;
  int tap = k >> 8, ic = k & 255;
  int dy = tap >> 1, dx = tap & 1;
  float val = 0.0f;
  if (ph < S * S) {
    int ry = ph / S, rx = ph % S;
    int ky = ry + S * dy, kx = rx + S * dx;
    if (ky < KSZ && kx < KSZ)
      val = w[((size_t)(ic * 2 + oc) * KSZ + ky) * KSZ + kx];
  }
  wr[idx] = f2bf(val);
}

// ---------------------------------------------------------------------------
// 1x1 conv (GEMM): Y[b][oc][n] = relu(bias[oc] + sum_k W[oc][k] * X[b][k][n])
// ---------------------------------------------------------------------------
__global__ __launch_bounds__(256) void conv1x1(const float* __restrict__ X,
    const float* __restrict__ Wt, const float* __restrict__ bias,
    u16* __restrict__ Y, int K, int N, int OCtot)
{
  __shared__ alignas(16) u16 Al[64][40];
  __shared__ alignas(16) u16 Bl[64][40];
  const int tid = threadIdx.x;
  const int n0 = blockIdx.x * 64, m0 = blockIdx.y * 64, b = blockIdx.z;
  const int lane = tid & 63, wv = tid >> 6, wr = wv >> 1, wc = wv & 1;
  const int am = tid >> 2, akq = tid & 3;
  const int sn = tid & 63, kq = tid >> 6;
  const float* Xb = X + (size_t)b * K * N + n0 + sn;
  f32x4 acc00 = {0,0,0,0}, acc01 = {0,0,0,0}, acc10 = {0,0,0,0}, acc11 = {0,0,0,0};
  for (int k0 = 0; k0 < K; k0 += 32) {
    s16x8 avv, bvv;
#pragma unroll
    for (int i = 0; i < 8; ++i)
      avv[i] = (short)f2bf(Wt[(size_t)(m0 + am) * K + k0 + akq * 8 + i]);
#pragma unroll
    for (int i = 0; i < 8; ++i)
      bvv[i] = (short)f2bf(Xb[(size_t)(k0 + kq * 8 + i) * N]);
    __syncthreads();
    *(s16x8*)&Al[am][akq * 8] = avv;
    *(s16x8*)&Bl[sn][kq * 8] = bvv;
    __syncthreads();
    const int fr = lane & 15, kg = (lane >> 4) * 8;
    s16x8 a0 = *(const s16x8*)&Al[wr * 32 + fr][kg];
    s16x8 a1 = *(const s16x8*)&Al[wr * 32 + 16 + fr][kg];
    s16x8 b0 = *(const s16x8*)&Bl[wc * 32 + fr][kg];
    s16x8 b1 = *(const s16x8*)&Bl[wc * 32 + 16 + fr][kg];
    acc00 = __builtin_amdgcn_mfma_f32_16x16x32_bf16(a0, b0, acc00, 0, 0, 0);
    acc01 = __builtin_amdgcn_mfma_f32_16x16x32_bf16(a0, b1, acc01, 0, 0, 0);
    acc10 = __builtin_amdgcn_mfma_f32_16x16x32_bf16(a1, b0, acc10, 0, 0, 0);
    acc11 = __builtin_amdgcn_mfma_f32_16x16x32_bf16(a1, b1, acc11, 0, 0, 0);
  }
  const int col = lane & 15, rg = (lane >> 4) * 4;
#define CV_ST(ACC, I, J) { \
    _Pragma("unroll") for (int r = 0; r < 4; ++r) { \
      int oc = m0 + wr * 32 + (I) * 16 + rg + r; \
      int nn = n0 + wc * 32 + (J) * 16 + col; \
      float v = ACC[r] + bias[oc]; \
      v = fmaxf(v, 0.0f); \
      Y[((size_t)b * OCtot + oc) * N + nn] = f2bf(v); } }
  CV_ST(acc00, 0, 0) CV_ST(acc01, 0, 1) CV_ST(acc10, 1, 0) CV_ST(acc11, 1, 1)
#undef CV_ST
}

// ---------------------------------------------------------------------------
// 3x3 conv pad1 + relu, implicit GEMM. X: [B][IC][WD*WD] bf16.
// ---------------------------------------------------------------------------
template<int WD>
__global__ __launch_bounds__(256) void blend3x3(const u16* __restrict__ X,
    const u16* __restrict__ Wr, const float* __restrict__ bias,
    u16* __restrict__ Y, int IC, int ICp)
{
  constexpr int HW = WD * WD;
  __shared__ alignas(16) u16 Al[64][40];
  __shared__ alignas(16) u16 Bl[64][40];
  const int tid = threadIdx.x;
  const int n0 = blockIdx.x * 64, m0 = blockIdx.y * 64, b = blockIdx.z;
  const int lane = tid & 63, wv = tid >> 6, wr = wv >> 1, wc = wv & 1;
  const int am = tid >> 2, akq = tid & 3;
  const int sn = tid & 63, kq = tid >> 6;
  const int pix = n0 + sn;
  const int py = pix / WD, px = pix % WD;
  const u16* Xb = X + (size_t)b * IC * HW;
  f32x4 acc00 = {0,0,0,0}, acc01 = {0,0,0,0}, acc10 = {0,0,0,0}, acc11 = {0,0,0,0};
  for (int tap = 0; tap < 9; ++tap) {
    const int dy = tap / 3 - 1, dx = tap % 3 - 1;
    const int sy = py + dy, sx = px + dx;
    const bool vsp = ((unsigned)sy < (unsigned)WD) && ((unsigned)sx < (unsigned)WD);
    const u16* Xt = Xb + sy * WD + sx;
    const u16* Wt = Wr + (size_t)tap * 256 * ICp;
    for (int k0 = 0; k0 < ICp; k0 += 32) {
      s16x8 avv = *(const s16x8*)&Wt[(size_t)(m0 + am) * ICp + k0 + akq * 8];
      s16x8 bvv;
#pragma unroll
      for (int i = 0; i < 8; ++i) {
        int k = k0 + kq * 8 + i;
        bool ok = vsp && (k < IC);
        bvv[i] = ok ? (short)Xt[(size_t)k * HW] : (short)0;
      }
      __syncthreads();
      *(s16x8*)&Al[am][akq * 8] = avv;
      *(s16x8*)&Bl[sn][kq * 8] = bvv;
      __syncthreads();
      const int fr = lane & 15, kg = (lane >> 4) * 8;
      s16x8 a0 = *(const s16x8*)&Al[wr * 32 + fr][kg];
      s16x8 a1 = *(const s16x8*)&Al[wr * 32 + 16 + fr][kg];
      s16x8 b0 = *(const s16x8*)&Bl[wc * 32 + fr][kg];
      s16x8 b1 = *(const s16x8*)&Bl[wc * 32 + 16 + fr][kg];
      acc00 = __builtin_amdgcn_mfma_f32_16x16x32_bf16(a0, b0, acc00, 0, 0, 0);
      acc01 = __builtin_amdgcn_mfma_f32_16x16x32_bf16(a0, b1, acc01, 0, 0, 0);
      acc10 = __builtin_amdgcn_mfma_f32_16x16x32_bf16(a1, b0, acc10, 0, 0, 0);
      acc11 = __builtin_amdgcn_mfma_f32_16x16x32_bf16(a1, b1, acc11, 0, 0, 0);
    }
  }
  const int col = lane & 15, rg = (lane >> 4) * 4;
#define BL_ST(ACC, I, J) { \
    _Pragma("unroll") for (int r = 0; r < 4; ++r) { \
      int oc = m0 + wr * 32 + (I) * 16 + rg + r; \
      int nn = n0 + wc * 32 + (J) * 16 + col; \
      float v = ACC[r] + bias[oc]; \
      v = fmaxf(v, 0.0f); \
      Y[((size_t)b * 256 + oc) * HW + nn] = f2bf(v); } }
  BL_ST(acc00, 0, 0) BL_ST(acc01, 0, 1) BL_ST(acc10, 1, 0) BL_ST(acc11, 1, 1)
#undef BL_ST
}

// ---------------------------------------------------------------------------
// Deconv as GEMM (phase decomposition). oy = S*ty + ry - 1 unique.
// A = Wr[MT*16][1024] bf16, B = shifted X views, N = (WIN+1)^2 per batch.
// ---------------------------------------------------------------------------
template<int S, int WIN, int MT, bool F32OUT>
__global__ __launch_bounds__(256) void deconv_gemm(const u16* __restrict__ X,
    const u16* __restrict__ Wr, const float* __restrict__ bias,
    void* __restrict__ Yout, int OCtot, int coff)
{
  constexpr int NP1 = WIN + 1;
  constexpr int Np = NP1 * NP1;
  constexpr int WO = S * WIN;
  constexpr int HWin = WIN * WIN;
  __shared__ alignas(16) u16 Al[MT * 16][40];
  __shared__ alignas(16) u16 Bl[64][40];
  const int tid = threadIdx.x;
  const int n0 = blockIdx.x * 64, b = blockIdx.y;
  const int lane = tid & 63, wv = tid >> 6;
  const int sn = tid & 63, kq = tid >> 6;
  const u16* Xb = X + (size_t)b * 256 * HWin;
  const int pixn = n0 + sn;
  const int t_y = pixn / NP1, t_x = pixn % NP1;
  f32x4 acc[MT];
#pragma unroll
  for (int mt = 0; mt < MT; ++mt) acc[mt] = (f32x4){0, 0, 0, 0};
  for (int k0 = 0; k0 < 1024; k0 += 32) {
    const int tap = k0 >> 8, dy = tap >> 1, dx = tap & 1;
    const int iy = t_y - dy, ix = t_x - dx;
    const bool vsp = (pixn < Np) && ((unsigned)iy < (unsigned)WIN) && ((unsigned)ix < (unsigned)WIN);
    const u16* Xt = Xb + iy * WIN + ix;
    const int icb = (k0 & 255) + kq * 8;
    s16x8 bvv;
#pragma unroll
    for (int i = 0; i < 8; ++i)
      bvv[i] = vsp ? (short)Xt[(size_t)(icb + i) * HWin] : (short)0;
    constexpr int PER = MT * 2;  // u16 per thread for A stage
    const int abase = tid * PER;
    const int arow = abase >> 5, akk = abase & 31;
    u16 av[PER];
#pragma unroll
    for (int i = 0; i < PER; ++i)
      av[i] = Wr[(size_t)arow * 1024 + k0 + akk + i];
    __syncthreads();
#pragma unroll
    for (int i = 0; i < PER; ++i) Al[arow][akk + i] = av[i];
    *(s16x8*)&Bl[sn][kq * 8] = bvv;
    __syncthreads();
    const int fr = lane & 15, kg = (lane >> 4) * 8;
    s16x8 bfrag = *(const s16x8*)&Bl[wv * 16 + fr][kg];
#pragma unroll
    for (int mt = 0; mt < MT; ++mt) {
      s16x8 afrag = *(const s16x8*)&Al[mt * 16 + fr][kg];
      acc[mt] = __builtin_amdgcn_mfma_f32_16x16x32_bf16(afrag, bfrag, acc[mt], 0, 0, 0);
    }
  }
  const int col = lane & 15, rg = (lane >> 4) * 4;
  const int nn = n0 + wv * 16 + col;
  if (nn >= Np) return;
  const int oty = nn / NP1, otx = nn % NP1;
#pragma unroll
  for (int mt = 0; mt < MT; ++mt) {
#pragma unroll
    for (int r = 0; r < 4; ++r) {
      int m = mt * 16 + rg + r;
      int ph = m >> 1, oc = m & 1;
      if (ph >= S * S) continue;
      int ry = ph / S, rx = ph % S;
      int oy = S * oty + ry - 1, ox = S * otx + rx - 1;
      if ((unsigned)oy >= (unsigned)WO || (unsigned)ox >= (unsigned)WO) continue;
      float v = acc[mt][r] + bias[oc];
      if (F32OUT)
        ((float*)Yout)[((size_t)b * 2 + oc) * WO * WO + (size_t)oy * WO + ox] = v;
      else
        ((u16*)Yout)[((size_t)b * OCtot + coff + oc) * WO * WO + (size_t)oy * WO + ox] = f2bf(v);
    }
  }
}

// ---------------------------------------------------------------------------
extern "C" void kernel_launch(void* const* d_in, const int* in_sizes, int n_in,
                              void* d_out, int out_size, void* d_ws, size_t ws_size,
                              hipStream_t stream)
{
  const float* feats_s16 = (const float*)d_in[0];
  const float* feats_s8  = (const float*)d_in[1];
  const float* feats_s4  = (const float*)d_in[2];
  const float* key       = (const float*)d_in[3];
  const float* init_key  = (const float*)d_in[4];
  const float* prev_key  = (const float*)d_in[5];
  const float* init_seg  = (const float*)d_in[6];
  const float* prev_seg  = (const float*)d_in[7];
  const float* mask_f    = (const float*)d_in[8];
  const float* w_conv1 = (const float*)d_in[9];  const float* b_conv1 = (const float*)d_in[10];
  const float* w_blend1= (const float*)d_in[11]; const float* b_blend1= (const float*)d_in[12];
  const float* w_dec1  = (const float*)d_in[13]; const float* b_dec1  = (const float*)d_in[14];
  const float* w_conv2 = (const float*)d_in[15]; const float* b_conv2 = (const float*)d_in[16];
  const float* w_blend2= (const float*)d_in[17]; const float* b_blend2= (const float*)d_in[18];
  const float* w_dec2  = (const float*)d_in[19]; const float* b_dec2  = (const float*)d_in[20];
  const float* w_conv3 = (const float*)d_in[21]; const float* b_conv3 = (const float*)d_in[22];
  const float* w_blend3= (const float*)d_in[23]; const float* b_blend3= (const float*)d_in[24];
  const float* w_dec3  = (const float*)d_in[25]; const float* b_dec3  = (const float*)d_in[26];

  char* ws = (char*)d_ws;
  size_t o = 0;
  auto take = [&](size_t n) { size_t r = o; o += (n + 255) & ~(size_t)255; return r; };
  float* simG = (float*)(ws + take((size_t)2 * 2304 * 2304 * 4));
  float* simL = (float*)(ws + take((size_t)2 * 2304 * 2304 * 4));
  float* cutv = (float*)(ws + take((size_t)2 * 2304 * 4));
  float* mnv  = (float*)(ws + take((size_t)2 * 2304 * 4));
  float* msc  = (float*)(ws + take((size_t)2 * 4 * 2304 * 4));
  u16* x1  = (u16*)(ws + take((size_t)2 * 516 * 2304 * 2));
  u16* b1o = (u16*)(ws + take((size_t)2 * 256 * 2304 * 2));
  u16* x2  = (u16*)(ws + take((size_t)2 * 258 * 9216 * 2));
  u16* b2o = (u16*)(ws + take((size_t)2 * 256 * 9216 * 2));
  u16* x3  = (u16*)(ws + take((size_t)2 * 258 * 36864 * 2));
  u16* b3o = (u16*)(ws + take((size_t)2 * 256 * 36864 * 2));
  u16* wr1 = (u16*)(ws + take((size_t)9 * 256 * 544 * 2));
  u16* wr2 = (u16*)(ws + take((size_t)9 * 256 * 288 * 2));
  u16* wr3 = (u16*)(ws + take((size_t)9 * 256 * 288 * 2));
  u16* wd1r = (u16*)(ws + take((size_t)16 * 1024 * 2));
  u16* wd2r = (u16*)(ws + take((size_t)16 * 1024 * 2));
  u16* wd3r = (u16*)(ws + take((size_t)32 * 1024 * 2));
  if (o > ws_size) {
    fprintf(stderr, "kernel_launch: ws too small: need %zu, have %zu\n", o, ws_size);
    return;
  }

  // weight repacks (fp32 -> bf16)
  repack<<<dim3((9 * 256 * 544 + 255) / 256), 256, 0, stream>>>(w_blend1, wr1, 516, 544);
  repack<<<dim3((9 * 256 * 288 + 255) / 256), 256, 0, stream>>>(w_blend2, wr2, 258, 288);
  repack<<<dim3((9 * 256 * 288 + 255) / 256), 256, 0, stream>>>(w_blend3, wr3, 258, 288);
  repack_dec<<<dim3(64), 256, 0, stream>>>(w_dec1, wd1r, 2, 4, 1);
  repack_dec<<<dim3(64), 256, 0, stream>>>(w_dec2, wd2r, 2, 4, 1);
  repack_dec<<<dim3(128), 256, 0, stream>>>(w_dec3, wd3r, 4, 6, 2);

  // similarity matrices
  sim_gemm<<<dim3(36, 36, 2), 256, 0, stream>>>(init_key, key, simG);
  sim_gemm<<<dim3(36, 36, 2), 256, 0, stream>>>(prev_key, key, simL);

  // matching scores
  rowstats<<<dim3(2 * 2304), 256, 0, stream>>>(simL, cutv, mnv);
  zero_f<<<dim3(72), 256, 0, stream>>>(msc, 2 * 4 * 2304);
  score_global<<<dim3(9, 18, 2), 256, 0, stream>>>(simG, init_seg, msc, 0);
  score_local<<<dim3(9, 18, 2), 256, 0, stream>>>(simL, prev_seg, cutv, mnv, msc, 2);

  // stage 1
  conv1x1<<<dim3(36, 4, 2), 256, 0, stream>>>(feats_s16, w_conv1, b_conv1, x1, 1024, 2304, 516);
  fill_scores<<<dim3(72), 256, 0, stream>>>(msc, x1);
  copy_mask<<<dim3(4608), 256, 0, stream>>>(mask_f, x1);
  blend3x3<48><<<dim3(36, 4, 2), 256, 0, stream>>>(x1, wr1, b_blend1, b1o, 516, 544);
  deconv_gemm<2, 48, 1, false><<<dim3((49 * 49 + 63) / 64, 2), 256, 0, stream>>>(
      b1o, wd1r, b_dec1, x2, 258, 256);

  // stage 2
  conv1x1<<<dim3(144, 4, 2), 256, 0, stream>>>(feats_s8, w_conv2, b_conv2, x2, 512, 9216, 258);
  blend3x3<96><<<dim3(144, 4, 2), 256, 0, stream>>>(x2, wr2, b_blend2, b2o, 258, 288);
  deconv_gemm<2, 96, 1, false><<<dim3((97 * 97 + 63) / 64, 2), 256, 0, stream>>>(
      b2o, wd2r, b_dec2, x3, 258, 256);

  // stage 3
  conv1x1<<<dim3(576, 4, 2), 256, 0, stream>>>(feats_s4, w_conv3, b_conv3, x3, 256, 36864, 258);
  blend3x3<192><<<dim3(576, 4, 2), 256, 0, stream>>>(x3, wr3, b_blend3, b3o, 258, 288);
  deconv_gemm<4, 192, 2, true><<<dim3((193 * 193 + 63) / 64, 2), 256, 0, stream>>>(
      b3o, wd3r, b_dec3, d_out, 2, 0);
}

// Round 5
// 788.329 us; speedup vs baseline: 1.6837x; 1.0102x over previous
//
#include <hip/hip_runtime.h>
#include <cstdio>

typedef unsigned short u16;
typedef __attribute__((ext_vector_type(4))) float f32x4;
typedef __attribute__((ext_vector_type(8))) short s16x8;

#define DEV static __device__ __forceinline__

DEV float bf2f(u16 u) { union { unsigned int i; float f; } v; v.i = ((unsigned int)u) << 16; return v.f; }
DEV u16 f2bf(float f) {
  unsigned int x = __float_as_uint(f);
  unsigned int r = (x + 0x7fffu + ((x >> 16) & 1u)) >> 16;
  return (u16)r;
}

// ---------------------------------------------------------------------------
// Similarity GEMM: out[b][p][q] = (dot(A[b,:,p], B[b,:,q]) + 1) * 0.5  (fp32)
// ---------------------------------------------------------------------------
__global__ __launch_bounds__(256) void sim_gemm(const float* __restrict__ A,
    const float* __restrict__ Bm, float* __restrict__ out)
{
  __shared__ alignas(16) u16 Al[64][40];
  __shared__ alignas(16) u16 Bl[64][40];
  const int tid = threadIdx.x;
  const int bm = blockIdx.x, bn = blockIdx.y, b = blockIdx.z;
  const int lane = tid & 63, wv = tid >> 6, wr = wv >> 1, wc = wv & 1;
  const int smi = tid & 63, kq = tid >> 6;
  const float* Ab = A + (size_t)b * 512 * 2304 + bm * 64 + smi;
  const float* Bb = Bm + (size_t)b * 512 * 2304 + bn * 64 + smi;
  f32x4 acc00 = {0,0,0,0}, acc01 = {0,0,0,0}, acc10 = {0,0,0,0}, acc11 = {0,0,0,0};
  for (int k0 = 0; k0 < 512; k0 += 32) {
    s16x8 avv, bvv;
#pragma unroll
    for (int i = 0; i < 8; ++i) {
      const size_t ko = (size_t)(k0 + kq * 8 + i) * 2304;
      avv[i] = (short)f2bf(Ab[ko]);
      bvv[i] = (short)f2bf(Bb[ko]);
    }
    __syncthreads();
    *(s16x8*)&Al[smi][kq * 8] = avv;
    *(s16x8*)&Bl[smi][kq * 8] = bvv;
    __syncthreads();
    const int fr = lane & 15, kg = (lane >> 4) * 8;
    s16x8 a0 = *(const s16x8*)&Al[wr * 32 + fr][kg];
    s16x8 a1 = *(const s16x8*)&Al[wr * 32 + 16 + fr][kg];
    s16x8 b0 = *(const s16x8*)&Bl[wc * 32 + fr][kg];
    s16x8 b1 = *(const s16x8*)&Bl[wc * 32 + 16 + fr][kg];
    acc00 = __builtin_amdgcn_mfma_f32_16x16x32_bf16(a0, b0, acc00, 0, 0, 0);
    acc01 = __builtin_amdgcn_mfma_f32_16x16x32_bf16(a0, b1, acc01, 0, 0, 0);
    acc10 = __builtin_amdgcn_mfma_f32_16x16x32_bf16(a1, b0, acc10, 0, 0, 0);
    acc11 = __builtin_amdgcn_mfma_f32_16x16x32_bf16(a1, b1, acc11, 0, 0, 0);
  }
  float* ob = out + ((size_t)b * 2304 + bm * 64) * 2304 + bn * 64;
  const int col = lane & 15, rg = (lane >> 4) * 4;
#define SIM_ST(ACC, I, J) { \
    _Pragma("unroll") for (int r = 0; r < 4; ++r) { \
      int row = wr * 32 + (I) * 16 + rg + r; \
      int c = wc * 32 + (J) * 16 + col; \
      ob[(size_t)row * 2304 + c] = (ACC[r] + 1.0f) * 0.5f; } }
  SIM_ST(acc00, 0, 0) SIM_ST(acc01, 0, 1) SIM_ST(acc10, 1, 0) SIM_ST(acc11, 1, 1)
#undef SIM_ST
}

// ---------------------------------------------------------------------------
// Per-row stats of local_sim: cut = 4th-largest over q, mn = min over q.
// ---------------------------------------------------------------------------
__global__ __launch_bounds__(256) void rowstats(const float* __restrict__ simL,
    float* __restrict__ cutv, float* __restrict__ mnv)
{
  const int row = blockIdx.x;
  const int tid = threadIdx.x;
  const float* r = simL + (size_t)row * 2304;
  float t0 = -1e30f, t1 = -1e30f, t2 = -1e30f, t3 = -1e30f, mn = 1e30f;
  for (int i = tid; i < 2304; i += 256) {
    float v = r[i];
    mn = fminf(mn, v);
    if (v > t3) {
      if (v > t2) { t3 = t2; if (v > t1) { t2 = t1; if (v > t0) { t1 = t0; t0 = v; } else t1 = v; } else t2 = v; }
      else t3 = v;
    }
  }
  __shared__ float s4[256][4];
  __shared__ float smv[256];
  s4[tid][0] = t0; s4[tid][1] = t1; s4[tid][2] = t2; s4[tid][3] = t3;
  smv[tid] = mn;
  __syncthreads();
  for (int s = 128; s > 0; s >>= 1) {
    if (tid < s) {
      float a0 = s4[tid][0], a1 = s4[tid][1], a2 = s4[tid][2], a3 = s4[tid][3];
      float b0 = s4[tid + s][0], b1 = s4[tid + s][1], b2 = s4[tid + s][2], b3 = s4[tid + s][3];
      float m0 = fmaxf(a0, b3), m1 = fmaxf(a1, b2), m2 = fmaxf(a2, b1), m3 = fmaxf(a3, b0);
      float c0 = fmaxf(m0, m2), c2 = fminf(m0, m2), c1 = fmaxf(m1, m3), c3 = fminf(m1, m3);
      s4[tid][0] = fmaxf(c0, c1); s4[tid][1] = fminf(c0, c1);
      s4[tid][2] = fmaxf(c2, c3); s4[tid][3] = fminf(c2, c3);
      smv[tid] = fminf(smv[tid], smv[tid + s]);
    }
    __syncthreads();
  }
  if (tid == 0) { cutv[row] = s4[0][3]; mnv[row] = smv[0]; }
}

__global__ __launch_bounds__(256) void zero_f(float* __restrict__ p, int n)
{
  int i = blockIdx.x * 256 + threadIdx.x;
  if (i < n) p[i] = 0.0f;
}

// global score: msc[b][chBase+c][q] = max_p sim[b][p][q] * seg[b][c][p]
__global__ __launch_bounds__(256) void score_global(const float* __restrict__ sim,
    const float* __restrict__ seg, float* __restrict__ msc, int chBase)
{
  const int b = blockIdx.z;
  const int q = blockIdx.x * 256 + threadIdx.x;
  const int p0 = blockIdx.y * 128;
  const float* sp = sim + ((size_t)b * 2304 + p0) * 2304 + q;
  const float* sg = seg + (size_t)b * 2 * 2304;
  float m0 = 0.0f, m1 = 0.0f;
  for (int p = 0; p < 128; ++p) {
    float sv = sp[(size_t)p * 2304];
    float s0 = sg[p0 + p];
    float s1 = sg[2304 + p0 + p];
    m0 = fmaxf(m0, sv * s0);
    m1 = fmaxf(m1, sv * s1);
  }
  atomicMax((int*)&msc[((size_t)b * 4 + chBase) * 2304 + q], __float_as_int(m0));
  atomicMax((int*)&msc[((size_t)b * 4 + chBase + 1) * 2304 + q], __float_as_int(m1));
}

// local score with per-row top4 threshold masking
__global__ __launch_bounds__(256) void score_local(const float* __restrict__ sim,
    const float* __restrict__ seg, const float* __restrict__ cutv,
    const float* __restrict__ mnv, float* __restrict__ msc, int chBase)
{
  const int b = blockIdx.z;
  const int q = blockIdx.x * 256 + threadIdx.x;
  const int p0 = blockIdx.y * 128;
  const float* sp = sim + ((size_t)b * 2304 + p0) * 2304 + q;
  const float* sg = seg + (size_t)b * 2 * 2304;
  const float* cu = cutv + (size_t)b * 2304 + p0;
  const float* ml = mnv + (size_t)b * 2304 + p0;
  float m0 = 0.0f, m1 = 0.0f;
  for (int p = 0; p < 128; ++p) {
    float sv = sp[(size_t)p * 2304];
    float cut = cu[p], mnr = ml[p];
    float mv = (sv < cut) ? mnr : sv;
    float s0 = sg[p0 + p];
    float s1 = sg[2304 + p0 + p];
    m0 = fmaxf(m0, mv * s0);
    m1 = fmaxf(m1, mv * s1);
  }
  atomicMax((int*)&msc[((size_t)b * 4 + chBase) * 2304 + q], __float_as_int(m0));
  atomicMax((int*)&msc[((size_t)b * 4 + chBase + 1) * 2304 + q], __float_as_int(m1));
}

// scores fp32 -> bf16 into x1 channels 256..259
__global__ __launch_bounds__(256) void fill_scores(const float* __restrict__ msc,
    u16* __restrict__ x1)
{
  int idx = blockIdx.x * 256 + threadIdx.x;
  if (idx >= 2 * 4 * 2304) return;
  int b = idx / (4 * 2304);
  int r = idx % (4 * 2304);
  int c = r / 2304, q = r % 2304;
  x1[((size_t)b * 516 + 256 + c) * 2304 + q] = f2bf(msc[idx]);
}

// mask_feats fp32 -> x1 channels 260..515 bf16
__global__ __launch_bounds__(256) void copy_mask(const float* __restrict__ mask,
    u16* __restrict__ x1)
{
  int idx = blockIdx.x * 256 + threadIdx.x;
  if (idx >= 2 * 256 * 2304) return;
  int b = idx / (256 * 2304);
  int r = idx % (256 * 2304);
  x1[(size_t)b * 516 * 2304 + 260 * 2304 + r] = f2bf(mask[idx]);
}

// repack blend weights: w[oc][ic][3][3] fp32 -> wr[tap][oc][ICp] bf16 (zero-pad ic)
__global__ __launch_bounds__(256) void repack(const float* __restrict__ w,
    u16* __restrict__ wr, int IC, int ICp)
{
  int idx = blockIdx.x * 256 + threadIdx.x;
  int total = 9 * 256 * ICp;
  if (idx >= total) return;
  int ic = idx % ICp;
  int oc = (idx / ICp) % 256;
  int tap = idx / (ICp * 256);
  wr[idx] = (ic < IC) ? f2bf(w[((size_t)oc * IC + ic) * 9 + tap]) : (u16)0;
}

// repack deconv weights: w[ic][oc][KSZ][KSZ] fp32 -> wr[MT*16][1024] bf16.
__global__ __launch_bounds__(256) void repack_dec(const float* __restrict__ w,
    u16* __restrict__ wr, int S, int KSZ, int MT)
{
  int idx = blockIdx.x * 256 + threadIdx.x;
  int total = MT * 16 * 1024;
  if (idx >= total) return;
  int m = idx >> 10, k = idx & 1023;
  int oc = m & 1, ph = m >> 1;
  int tap = k >> 8, ic = k & 255;
  int dy = tap >> 1, dx = tap & 1;
  float val = 0.0f;
  if (ph < S * S) {
    int ry = ph / S, rx = ph % S;
    int ky = ry + S * dy, kx = rx + S * dx;
    if (ky < KSZ && kx < KSZ)
      val = w[((size_t)(ic * 2 + oc) * KSZ + ky) * KSZ + kx];
  }
  wr[idx] = f2bf(val);
}

// ---------------------------------------------------------------------------
// 1x1 conv (GEMM), MB oc-rows x 64 pixels per block, fragment-linear LDS.
// Wave wv owns subtiles s = wv*SPW + p (p<SPW), i.e. MB/4 contiguous oc rows.
// grid: (N/64, 256/MB, B).
// ---------------------------------------------------------------------------
template<int MB>
__global__ __launch_bounds__(256) void conv1x1_mb(const float* __restrict__ X,
    const float* __restrict__ Wt, const float* __restrict__ bias,
    u16* __restrict__ Y, int K, int N, int OCtot)
{
  constexpr int SUB = MB / 16;   // A subtiles
  constexpr int SPW = SUB / 4;   // subtiles per wave
  __shared__ alignas(16) u16 Alin[SUB][64][8];
  __shared__ alignas(16) u16 Blin[4][64][8];
  const int tid = threadIdx.x;
  const int n0 = blockIdx.x * 64, m0 = blockIdx.y * MB, b = blockIdx.z;
  const int lane = tid & 63, wv = tid >> 6;
  const int fr = lane & 15, kq = lane >> 4;
  const float* Xb = X + (size_t)b * K * N;
  const int bpix = n0 + wv * 16 + fr;  // pixel this thread stages for B subtile wv
  f32x4 acc[SPW][4];
#pragma unroll
  for (int p = 0; p < SPW; ++p)
#pragma unroll
    for (int j = 0; j < 4; ++j) acc[p][j] = (f32x4){0, 0, 0, 0};
  for (int k0 = 0; k0 < K; k0 += 32) {
    s16x8 areg[SPW];
#pragma unroll
    for (int p = 0; p < SPW; ++p) {
      const float* wp = Wt + (size_t)(m0 + (wv * SPW + p) * 16 + fr) * K + k0 + kq * 8;
#pragma unroll
      for (int i = 0; i < 8; ++i) areg[p][i] = (short)f2bf(wp[i]);
    }
    s16x8 breg;
#pragma unroll
    for (int i = 0; i < 8; ++i)
      breg[i] = (short)f2bf(Xb[(size_t)(k0 + kq * 8 + i) * N + bpix]);
    __syncthreads();
#pragma unroll
    for (int p = 0; p < SPW; ++p) *(s16x8*)&Alin[wv * SPW + p][lane][0] = areg[p];
    *(s16x8*)&Blin[wv][lane][0] = breg;
    __syncthreads();
    s16x8 bfr[4];
#pragma unroll
    for (int j = 0; j < 4; ++j) bfr[j] = *(const s16x8*)&Blin[j][lane][0];
#pragma unroll
    for (int p = 0; p < SPW; ++p) {
      s16x8 afr = *(const s16x8*)&Alin[wv * SPW + p][lane][0];
#pragma unroll
      for (int j = 0; j < 4; ++j)
        acc[p][j] = __builtin_amdgcn_mfma_f32_16x16x32_bf16(afr, bfr[j], acc[p][j], 0, 0, 0);
    }
  }
  const int col = lane & 15, rg = (lane >> 4) * 4;
#pragma unroll
  for (int p = 0; p < SPW; ++p)
#pragma unroll
    for (int j = 0; j < 4; ++j)
#pragma unroll
      for (int r = 0; r < 4; ++r) {
        int oc = m0 + (wv * SPW + p) * 16 + rg + r;
        int nn = n0 + j * 16 + col;
        float v = acc[p][j][r] + bias[oc];
        v = fmaxf(v, 0.0f);
        Y[((size_t)b * OCtot + oc) * N + nn] = f2bf(v);
      }
}

// ---------------------------------------------------------------------------
// 3x3 conv pad1 + relu, implicit GEMM, MB oc-rows x 64 pixels per block.
// X: [B][IC][WD*WD] bf16, Wr: [9][256][ICp] bf16. grid: (HW/64, 256/MB, B).
// ---------------------------------------------------------------------------
template<int WD, int MB>
__global__ __launch_bounds__(256) void blend3x3_mb(const u16* __restrict__ X,
    const u16* __restrict__ Wr, const float* __restrict__ bias,
    u16* __restrict__ Y, int IC, int ICp)
{
  constexpr int HW = WD * WD;
  constexpr int SUB = MB / 16;
  constexpr int SPW = SUB / 4;
  __shared__ alignas(16) u16 Alin[SUB][64][8];
  __shared__ alignas(16) u16 Blin[4][64][8];
  const int tid = threadIdx.x;
  const int n0 = blockIdx.x * 64, m0 = blockIdx.y * MB, b = blockIdx.z;
  const int lane = tid & 63, wv = tid >> 6;
  const int fr = lane & 15, kq = lane >> 4;
  const u16* Xb = X + (size_t)b * IC * HW;
  const int bpix = n0 + wv * 16 + fr;
  const int py = bpix / WD, px = bpix % WD;
  f32x4 acc[SPW][4];
#pragma unroll
  for (int p = 0; p < SPW; ++p)
#pragma unroll
    for (int j = 0; j < 4; ++j) acc[p][j] = (f32x4){0, 0, 0, 0};
  for (int tap = 0; tap < 9; ++tap) {
    const int dy = tap / 3 - 1, dx = tap % 3 - 1;
    const int sy = py + dy, sx = px + dx;
    const bool vsp = ((unsigned)sy < (unsigned)WD) && ((unsigned)sx < (unsigned)WD);
    const u16* Xt = Xb + sy * WD + sx;
    const u16* Wtap = Wr + (size_t)tap * 256 * ICp;
    for (int k0 = 0; k0 < ICp; k0 += 32) {
      s16x8 areg[SPW];
#pragma unroll
      for (int p = 0; p < SPW; ++p)
        areg[p] = *(const s16x8*)&Wtap[(size_t)(m0 + (wv * SPW + p) * 16 + fr) * ICp + k0 + kq * 8];
      s16x8 breg;
#pragma unroll
      for (int i = 0; i < 8; ++i) {
        int k = k0 + kq * 8 + i;
        bool ok = vsp && (k < IC);
        breg[i] = ok ? (short)Xt[(size_t)k * HW] : (short)0;
      }
      __syncthreads();
#pragma unroll
      for (int p = 0; p < SPW; ++p) *(s16x8*)&Alin[wv * SPW + p][lane][0] = areg[p];
      *(s16x8*)&Blin[wv][lane][0] = breg;
      __syncthreads();
      s16x8 bfr[4];
#pragma unroll
      for (int j = 0; j < 4; ++j) bfr[j] = *(const s16x8*)&Blin[j][lane][0];
#pragma unroll
      for (int p = 0; p < SPW; ++p) {
        s16x8 afr = *(const s16x8*)&Alin[wv * SPW + p][lane][0];
#pragma unroll
        for (int j = 0; j < 4; ++j)
          acc[p][j] = __builtin_amdgcn_mfma_f32_16x16x32_bf16(afr, bfr[j], acc[p][j], 0, 0, 0);
      }
    }
  }
  const int col = lane & 15, rg = (lane >> 4) * 4;
#pragma unroll
  for (int p = 0; p < SPW; ++p)
#pragma unroll
    for (int j = 0; j < 4; ++j)
#pragma unroll
      for (int r = 0; r < 4; ++r) {
        int oc = m0 + (wv * SPW + p) * 16 + rg + r;
        int nn = n0 + j * 16 + col;
        float v = acc[p][j][r] + bias[oc];
        v = fmaxf(v, 0.0f);
        Y[((size_t)b * 256 + oc) * HW + nn] = f2bf(v);
      }
}

// ---------------------------------------------------------------------------
// Deconv as GEMM (phase decomposition). oy = S*ty + ry - 1 unique.
// ---------------------------------------------------------------------------
template<int S, int WIN, int MT, bool F32OUT>
__global__ __launch_bounds__(256) void deconv_gemm(const u16* __restrict__ X,
    const u16* __restrict__ Wr, const float* __restrict__ bias,
    void* __restrict__ Yout, int OCtot, int coff)
{
  constexpr int NP1 = WIN + 1;
  constexpr int Np = NP1 * NP1;
  constexpr int WO = S * WIN;
  constexpr int HWin = WIN * WIN;
  __shared__ alignas(16) u16 Al[MT * 16][40];
  __shared__ alignas(16) u16 Bl[64][40];
  const int tid = threadIdx.x;
  const int n0 = blockIdx.x * 64, b = blockIdx.y;
  const int lane = tid & 63, wv = tid >> 6;
  const int sn = tid & 63, kq = tid >> 6;
  const u16* Xb = X + (size_t)b * 256 * HWin;
  const int pixn = n0 + sn;
  const int t_y = pixn / NP1, t_x = pixn % NP1;
  f32x4 acc[MT];
#pragma unroll
  for (int mt = 0; mt < MT; ++mt) acc[mt] = (f32x4){0, 0, 0, 0};
  for (int k0 = 0; k0 < 1024; k0 += 32) {
    const int tap = k0 >> 8, dy = tap >> 1, dx = tap & 1;
    const int iy = t_y - dy, ix = t_x - dx;
    const bool vsp = (pixn < Np) && ((unsigned)iy < (unsigned)WIN) && ((unsigned)ix < (unsigned)WIN);
    const u16* Xt = Xb + iy * WIN + ix;
    const int icb = (k0 & 255) + kq * 8;
    s16x8 bvv;
#pragma unroll
    for (int i = 0; i < 8; ++i)
      bvv[i] = vsp ? (short)Xt[(size_t)(icb + i) * HWin] : (short)0;
    constexpr int PER = MT * 2;
    const int abase = tid * PER;
    const int arow = abase >> 5, akk = abase & 31;
    u16 av[PER];
#pragma unroll
    for (int i = 0; i < PER; ++i)
      av[i] = Wr[(size_t)arow * 1024 + k0 + akk + i];
    __syncthreads();
#pragma unroll
    for (int i = 0; i < PER; ++i) Al[arow][akk + i] = av[i];
    *(s16x8*)&Bl[sn][kq * 8] = bvv;
    __syncthreads();
    const int fr = lane & 15, kg = (lane >> 4) * 8;
    s16x8 bfrag = *(const s16x8*)&Bl[wv * 16 + fr][kg];
#pragma unroll
    for (int mt = 0; mt < MT; ++mt) {
      s16x8 afrag = *(const s16x8*)&Al[mt * 16 + fr][kg];
      acc[mt] = __builtin_amdgcn_mfma_f32_16x16x32_bf16(afrag, bfrag, acc[mt], 0, 0, 0);
    }
  }
  const int col = lane & 15, rg = (lane >> 4) * 4;
  const int nn = n0 + wv * 16 + col;
  if (nn >= Np) return;
  const int oty = nn / NP1, otx = nn % NP1;
#pragma unroll
  for (int mt = 0; mt < MT; ++mt) {
#pragma unroll
    for (int r = 0; r < 4; ++r) {
      int m = mt * 16 + rg + r;
      int ph = m >> 1, oc = m & 1;
      if (ph >= S * S) continue;
      int ry = ph / S, rx = ph % S;
      int oy = S * oty + ry - 1, ox = S * otx + rx - 1;
      if ((unsigned)oy >= (unsigned)WO || (unsigned)ox >= (unsigned)WO) continue;
      float v = acc[mt][r] + bias[oc];
      if (F32OUT)
        ((float*)Yout)[((size_t)b * 2 + oc) * WO * WO + (size_t)oy * WO + ox] = v;
      else
        ((u16*)Yout)[((size_t)b * OCtot + coff + oc) * WO * WO + (size_t)oy * WO + ox] = f2bf(v);
    }
  }
}

// ---------------------------------------------------------------------------
extern "C" void kernel_launch(void* const* d_in, const int* in_sizes, int n_in,
                              void* d_out, int out_size, void* d_ws, size_t ws_size,
                              hipStream_t stream)
{
  const float* feats_s16 = (const float*)d_in[0];
  const float* feats_s8  = (const float*)d_in[1];
  const float* feats_s4  = (const float*)d_in[2];
  const float* key       = (const float*)d_in[3];
  const float* init_key  = (const float*)d_in[4];
  const float* prev_key  = (const float*)d_in[5];
  const float* init_seg  = (const float*)d_in[6];
  const float* prev_seg  = (const float*)d_in[7];
  const float* mask_f    = (const float*)d_in[8];
  const float* w_conv1 = (const float*)d_in[9];  const float* b_conv1 = (const float*)d_in[10];
  const float* w_blend1= (const float*)d_in[11]; const float* b_blend1= (const float*)d_in[12];
  const float* w_dec1  = (const float*)d_in[13]; const float* b_dec1  = (const float*)d_in[14];
  const float* w_conv2 = (const float*)d_in[15]; const float* b_conv2 = (const float*)d_in[16];
  const float* w_blend2= (const float*)d_in[17]; const float* b_blend2= (const float*)d_in[18];
  const float* w_dec2  = (const float*)d_in[19]; const float* b_dec2  = (const float*)d_in[20];
  const float* w_conv3 = (const float*)d_in[21]; const float* b_conv3 = (const float*)d_in[22];
  const float* w_blend3= (const float*)d_in[23]; const float* b_blend3= (const float*)d_in[24];
  const float* w_dec3  = (const float*)d_in[25]; const float* b_dec3  = (const float*)d_in[26];

  char* ws = (char*)d_ws;
  size_t o = 0;
  auto take = [&](size_t n) { size_t r = o; o += (n + 255) & ~(size_t)255; return r; };
  float* simG = (float*)(ws + take((size_t)2 * 2304 * 2304 * 4));
  float* simL = (float*)(ws + take((size_t)2 * 2304 * 2304 * 4));
  float* cutv = (float*)(ws + take((size_t)2 * 2304 * 4));
  float* mnv  = (float*)(ws + take((size_t)2 * 2304 * 4));
  float* msc  = (float*)(ws + take((size_t)2 * 4 * 2304 * 4));
  u16* x1  = (u16*)(ws + take((size_t)2 * 516 * 2304 * 2));
  u16* b1o = (u16*)(ws + take((size_t)2 * 256 * 2304 * 2));
  u16* x2  = (u16*)(ws + take((size_t)2 * 258 * 9216 * 2));
  u16* b2o = (u16*)(ws + take((size_t)2 * 256 * 9216 * 2));
  u16* x3  = (u16*)(ws + take((size_t)2 * 258 * 36864 * 2));
  u16* b3o = (u16*)(ws + take((size_t)2 * 256 * 36864 * 2));
  u16* wr1 = (u16*)(ws + take((size_t)9 * 256 * 544 * 2));
  u16* wr2 = (u16*)(ws + take((size_t)9 * 256 * 288 * 2));
  u16* wr3 = (u16*)(ws + take((size_t)9 * 256 * 288 * 2));
  u16* wd1r = (u16*)(ws + take((size_t)16 * 1024 * 2));
  u16* wd2r = (u16*)(ws + take((size_t)16 * 1024 * 2));
  u16* wd3r = (u16*)(ws + take((size_t)32 * 1024 * 2));
  if (o > ws_size) {
    fprintf(stderr, "kernel_launch: ws too small: need %zu, have %zu\n", o, ws_size);
    return;
  }

  // weight repacks (fp32 -> bf16)
  repack<<<dim3((9 * 256 * 544 + 255) / 256), 256, 0, stream>>>(w_blend1, wr1, 516, 544);
  repack<<<dim3((9 * 256 * 288 + 255) / 256), 256, 0, stream>>>(w_blend2, wr2, 258, 288);
  repack<<<dim3((9 * 256 * 288 + 255) / 256), 256, 0, stream>>>(w_blend3, wr3, 258, 288);
  repack_dec<<<dim3(64), 256, 0, stream>>>(w_dec1, wd1r, 2, 4, 1);
  repack_dec<<<dim3(64), 256, 0, stream>>>(w_dec2, wd2r, 2, 4, 1);
  repack_dec<<<dim3(128), 256, 0, stream>>>(w_dec3, wd3r, 4, 6, 2);

  // similarity matrices
  sim_gemm<<<dim3(36, 36, 2), 256, 0, stream>>>(init_key, key, simG);
  sim_gemm<<<dim3(36, 36, 2), 256, 0, stream>>>(prev_key, key, simL);

  // matching scores
  rowstats<<<dim3(2 * 2304), 256, 0, stream>>>(simL, cutv, mnv);
  zero_f<<<dim3(72), 256, 0, stream>>>(msc, 2 * 4 * 2304);
  score_global<<<dim3(9, 18, 2), 256, 0, stream>>>(simG, init_seg, msc, 0);
  score_local<<<dim3(9, 18, 2), 256, 0, stream>>>(simL, prev_seg, cutv, mnv, msc, 2);

  // stage 1  (inputs L2-resident -> MB=128 for parallelism)
  conv1x1_mb<128><<<dim3(36, 2, 2), 256, 0, stream>>>(feats_s16, w_conv1, b_conv1, x1, 1024, 2304, 516);
  fill_scores<<<dim3(72), 256, 0, stream>>>(msc, x1);
  copy_mask<<<dim3(4608), 256, 0, stream>>>(mask_f, x1);
  blend3x3_mb<48, 128><<<dim3(36, 2, 2), 256, 0, stream>>>(x1, wr1, b_blend1, b1o, 516, 544);
  deconv_gemm<2, 48, 1, false><<<dim3((49 * 49 + 63) / 64, 2), 256, 0, stream>>>(
      b1o, wd1r, b_dec1, x2, 258, 256);

  // stage 2
  conv1x1_mb<256><<<dim3(144, 1, 2), 256, 0, stream>>>(feats_s8, w_conv2, b_conv2, x2, 512, 9216, 258);
  blend3x3_mb<96, 256><<<dim3(144, 1, 2), 256, 0, stream>>>(x2, wr2, b_blend2, b2o, 258, 288);
  deconv_gemm<2, 96, 1, false><<<dim3((97 * 97 + 63) / 64, 2), 256, 0, stream>>>(
      b2o, wd2r, b_dec2, x3, 258, 256);

  // stage 3
  conv1x1_mb<256><<<dim3(576, 1, 2), 256, 0, stream>>>(feats_s4, w_conv3, b_conv3, x3, 256, 36864, 258);
  blend3x3_mb<192, 256><<<dim3(576, 1, 2), 256, 0, stream>>>(x3, wr3, b_blend3, b3o, 258, 288);
  deconv_gemm<4, 192, 2, true><<<dim3((193 * 193 + 63) / 64, 2), 256, 0, stream>>>(
      b3o, wd3r, b_dec3, d_out, 2, 0);
}